// Round 4
// baseline (282.094 us; speedup 1.0000x reference)
//
#include <hip/hip_runtime.h>
#include <hip/hip_bf16.h>
#include <stdint.h>

// KAN layer fused, MI355X (gfx950). R4.
// out[M=65536,N=256] (fp32) = A[M,K=256] @ W^T
//   A[m,k] = (c0[k]*B0(tanh x) + c1[k]*B1(tanh x))  (1/6 pre-folded into c) -> bf16, in REGISTERS
//   W bf16 in LDS, 64 KB per K-half, XOR-swizzled; staged twice per block.
// 3 lgkm-only barriers per block; x prefetched 1 iter ahead, stays in flight across barriers.
// __launch_bounds__(256,2): 256-VGPR budget -> no spills (R3 spilled ~195 MB at the 64-VGPR
// occupancy heuristic: WRITE_SIZE 66.5->261 MB with identical stores).

typedef __attribute__((ext_vector_type(8))) short short8;   // 8 bf16 (MFMA A/B frag)
typedef __attribute__((ext_vector_type(4))) float f32x4;    // MFMA C/D frag

__device__ __forceinline__ uint16_t f2bf(float f) {
    union { float f; uint32_t u; } v; v.f = f;
    uint32_t r = v.u + 0x7FFFu + ((v.u >> 16) & 1u);  // RNE
    return (uint16_t)(r >> 16);
}

__device__ __forceinline__ float cube_relu(float v) {
    float m = fmaxf(v, 0.0f);
    return m * m * m;
}

// c0,c1 come pre-scaled by 1/6 (done in conv_w)
__device__ __forceinline__ float inner_eval(float xx, float c0, float c1) {
    float e  = __expf(2.0f * xx);                         // tanh = 1 - 2/(e+1)
    float r  = __builtin_amdgcn_rcpf(e + 1.0f);
    float u  = fmaf(-7.0f, r, 7.0f);                      // (tanh+1)*3.5, in [0,7]
    float w0 = cube_relu(u);
    float w1 = cube_relu(u - 1.0f);
    float w2 = cube_relu(u - 2.0f);
    float w3 = cube_relu(u - 3.0f);
    float w4 = cube_relu(u - 4.0f);
    float w5 = cube_relu(u - 5.0f);
    float B0 = w0 - 4.0f*w1 + 6.0f*w2 - 4.0f*w3 + w4;
    float B1 = w1 - 4.0f*w2 + 6.0f*w3 - 4.0f*w4 + w5;
    return fmaf(c0, B0, c1 * B1);
}

// barrier that does NOT drain vmcnt: lgkmcnt=0, expcnt=7, vmcnt=63 -> 0xC07F
#define LGKM_BARRIER() do { \
    __asm__ volatile("" ::: "memory"); \
    __builtin_amdgcn_s_waitcnt(0xC07F); \
    __builtin_amdgcn_s_barrier(); \
    __asm__ volatile("" ::: "memory"); \
} while (0)

// W fp32 -> bf16 (65536 elems), plus coeff table ct[k] = (c0/6, c1/6)
__global__ void conv_w(const float4* __restrict__ wf, uint2* __restrict__ o,
                       const float* __restrict__ ic, float2* __restrict__ ct) {
    const int i = blockIdx.x * blockDim.x + threadIdx.x;  // 0..16383
    const float4 v = wf[i];
    uint2 r;
    r.x = (uint32_t)f2bf(v.x) | ((uint32_t)f2bf(v.y) << 16);
    r.y = (uint32_t)f2bf(v.z) | ((uint32_t)f2bf(v.w) << 16);
    o[i] = r;
    if (blockIdx.x == 0) {
        const int t = threadIdx.x;  // 0..255 == IN
        ct[t] = make_float2(ic[t * 5 + 0] * (1.0f / 6.0f), ic[t * 5 + 1] * (1.0f / 6.0f));
    }
}

// Block: 256 threads (4 waves), BM=64, BN=256 (wave w: n in [w*64,w*64+64)), grid 1024.
// LDS: W-half [256 n][128 k] bf16 = 64 KB, 16B chunks XOR-swizzled: chunk' = c ^ (n&15).
__global__ __launch_bounds__(256, 2)
void kan_fused(const float* __restrict__ x,
               const float2* __restrict__ ct,
               const uint16_t* __restrict__ wb,
               float* __restrict__ out)
{
    __shared__ uint16_t Wlds[256 * 128];   // 65536 B

    const int t    = threadIdx.x;
    const int lane = t & 63;
    const int w    = t >> 6;
    const int m0   = blockIdx.x * 64;
    const int mrow = lane & 15;
    const int quad = lane >> 4;
    const int nw   = w * 64;

    const float4* ctf4 = (const float4*)ct;   // 128 x float4 (2 KB, L1-hot)

    // per-lane x base: row m0+mrow (+i*16), col quad*8
    const float* xr0 = x + (size_t)(m0 + mrow) * 256 + quad * 8;

    // B-frag addressing precompute: n_j = nw + j*16 + mrow; (n_j & 15) == mrow
    int wboff[4];
    #pragma unroll
    for (int j = 0; j < 4; ++j) wboff[j] = (nw + j * 16 + mrow) * 128;

    // prefetch x for kk=0 (stays in flight across staging + barrier)
    float4 xa[4], xb[4];
    #pragma unroll
    for (int i = 0; i < 4; ++i) {
        const float* p = xr0 + i * 16 * 256;
        xa[i] = *(const float4*)(p);
        xb[i] = *(const float4*)(p + 4);
    }

    // ---- stage W half 0 into LDS (coalesced global -> swizzled ds_write) ----
    #pragma unroll
    for (int rep = 0; rep < 16; ++rep) {
        const int flat = rep * 256 + t;
        const int n = flat >> 4, c = flat & 15;
        short8 v = *(const short8*)(wb + n * 256 + c * 8);
        *(short8*)(&Wlds[n * 128 + ((c ^ (n & 15)) << 3)]) = v;
    }

    f32x4 acc[4][4];
    #pragma unroll
    for (int i = 0; i < 4; ++i)
        #pragma unroll
        for (int j = 0; j < 4; ++j)
            acc[i][j] = (f32x4){0.f, 0.f, 0.f, 0.f};

    LGKM_BARRIER();   // W half 0 visible

    #pragma unroll 1
    for (int kk = 0; kk < 8; ++kk) {
        if (kk == 4) {  // restage: W half 1 (wave-uniform branch)
            LGKM_BARRIER();   // all B-frag ds_reads of half 0 complete (lgkm)
            #pragma unroll
            for (int rep = 0; rep < 16; ++rep) {
                const int flat = rep * 256 + t;
                const int n = flat >> 4, c = flat & 15;
                short8 v = *(const short8*)(wb + n * 256 + 128 + c * 8);
                *(short8*)(&Wlds[n * 128 + ((c ^ (n & 15)) << 3)]) = v;
            }
            LGKM_BARRIER();   // half 1 visible; x prefetch (vm) untouched
        }
        const int kloc = kk & 3;

        // prefetch x for kk+1
        float4 nxa[4], nxb[4];
        if (kk < 7) {
            #pragma unroll
            for (int i = 0; i < 4; ++i) {
                const float* p = xr0 + i * 16 * 256 + (kk + 1) * 32;
                nxa[i] = *(const float4*)(p);
                nxb[i] = *(const float4*)(p + 4);
            }
        }

        // coeffs for this k-window (L1-hot 2 KB): 8 float2 = 4 float4
        float4 cf[4];
        #pragma unroll
        for (int u = 0; u < 4; ++u) cf[u] = ctf4[kk * 16 + quad * 4 + u];

        // B-frags from swizzled LDS (2-way bank conflicts = free)
        short8 bf[4];
        {
            const int cbase = kloc * 4 + quad;
            #pragma unroll
            for (int j = 0; j < 4; ++j)
                bf[j] = *(const short8*)(&Wlds[wboff[j] + ((cbase ^ mrow) << 3)]);
        }

        // A-frags: spline directly into registers (layout A[m=mrow(+16i)][k=quad*8+j])
        #pragma unroll
        for (int i = 0; i < 4; ++i) {
            uint32_t p0 = (uint32_t)f2bf(inner_eval(xa[i].x, cf[0].x, cf[0].y)) |
                          ((uint32_t)f2bf(inner_eval(xa[i].y, cf[0].z, cf[0].w)) << 16);
            uint32_t p1 = (uint32_t)f2bf(inner_eval(xa[i].z, cf[1].x, cf[1].y)) |
                          ((uint32_t)f2bf(inner_eval(xa[i].w, cf[1].z, cf[1].w)) << 16);
            uint32_t p2 = (uint32_t)f2bf(inner_eval(xb[i].x, cf[2].x, cf[2].y)) |
                          ((uint32_t)f2bf(inner_eval(xb[i].y, cf[2].z, cf[2].w)) << 16);
            uint32_t p3 = (uint32_t)f2bf(inner_eval(xb[i].z, cf[3].x, cf[3].y)) |
                          ((uint32_t)f2bf(inner_eval(xb[i].w, cf[3].z, cf[3].w)) << 16);
            union { uint32_t u[4]; short8 s; } af;
            af.u[0] = p0; af.u[1] = p1; af.u[2] = p2; af.u[3] = p3;
            #pragma unroll
            for (int j = 0; j < 4; ++j)
                acc[i][j] = __builtin_amdgcn_mfma_f32_16x16x32_bf16(af.s, bf[j], acc[i][j], 0, 0, 0);
        }

        if (kk < 7) {
            #pragma unroll
            for (int i = 0; i < 4; ++i) { xa[i] = nxa[i]; xb[i] = nxb[i]; }
        }
    }

    // epilogue: direct fp32 stores (R2-verified clean: WRITE_SIZE == 65 MB).
    // C/D layout: col = lane&15, row = quad*4 + reg. Each quad writes 64B contiguous.
    #pragma unroll
    for (int i = 0; i < 4; ++i) {
        #pragma unroll
        for (int r = 0; r < 4; ++r) {
            const size_t row = (size_t)(m0 + i * 16 + quad * 4 + r);
            float* orow = out + row * 256 + nw + mrow;
            #pragma unroll
            for (int j = 0; j < 4; ++j)
                orow[j * 16] = acc[i][j][r];
        }
    }
}

extern "C" void kernel_launch(void* const* d_in, const int* in_sizes, int n_in,
                              void* d_out, int out_size, void* d_ws, size_t ws_size,
                              hipStream_t stream) {
    const float* x  = (const float*)d_in[0];   // [16,4096,256] fp32
    const float* ic = (const float*)d_in[1];   // [256,5] fp32
    const float* oc = (const float*)d_in[2];   // [256,256] fp32

    uint16_t* wb = (uint16_t*)d_ws;                      // 128 KB bf16 W
    float2*   ct = (float2*)((char*)d_ws + 131072);      // 2 KB coeff/6 table

    conv_w<<<64, 256, 0, stream>>>((const float4*)oc, (uint2*)wb, ic, ct);
    kan_fused<<<1024, 256, 0, stream>>>(x, ct, wb, (float*)d_out);
}

// Round 5
// 159.701 us; speedup vs baseline: 1.7664x; 1.7664x over previous
//
#include <hip/hip_runtime.h>
#include <stdint.h>

// KAN layer, MI355X (gfx950). R5: zero-LDS, zero-barrier dataflow kernel.
// out[M=65536,N=256] (fp32) = A[M,K=256] @ W^T
//   A[m,k] = c0[k]*B0(tanh x[m,k]) + c1[k]*B1(tanh x[m,k])  (1/6 folded into c), bf16 in regs
// Wave mw owns rows [m0+16*mw, +16) x ALL n: each lane's spline outputs ARE its MFMA
// A-fragment -> no A sharing, no LDS, no barriers. B-frags read per chunk from a
// fragment-major bf16 W (pre-permuted by conv_w; one coalesced dwordx4 per lane per frag).
// R3/R4 lesson: allocator over-targets occupancy and spills (WRITE_SIZE 66->261/291 MB).
// amdgpu_waves_per_eu(2,2) pins an EXACT 256-VGPR budget: ~190 live regs -> no spill.

typedef __attribute__((ext_vector_type(8))) short short8;   // 8 bf16 (MFMA A/B frag)
typedef __attribute__((ext_vector_type(4))) float f32x4;    // MFMA C/D frag

__device__ __forceinline__ uint16_t f2bf(float f) {
    union { float f; uint32_t u; } v; v.f = f;
    uint32_t r = v.u + 0x7FFFu + ((v.u >> 16) & 1u);  // RNE
    return (uint16_t)(r >> 16);
}

__device__ __forceinline__ float cube_relu(float v) {
    float m = fmaxf(v, 0.0f);
    return m * m * m;
}

// c0,c1 pre-scaled by 1/6 (conv_w). Uniform knots h=2/7 on [-1,1]; u=(tanh+1)*3.5 in [0,7].
__device__ __forceinline__ float inner_eval(float xx, float c0, float c1) {
    float e  = __expf(2.0f * xx);                       // tanh = 1 - 2/(e+1)
    float r  = __builtin_amdgcn_rcpf(e + 1.0f);
    float u  = fmaf(-7.0f, r, 7.0f);
    float w0 = cube_relu(u);
    float w1 = cube_relu(u - 1.0f);
    float w2 = cube_relu(u - 2.0f);
    float w3 = cube_relu(u - 3.0f);
    float w4 = cube_relu(u - 4.0f);
    float w5 = cube_relu(u - 5.0f);
    float B0 = w0 - 4.0f*w1 + 6.0f*w2 - 4.0f*w3 + w4;
    float B1 = w1 - 4.0f*w2 + 6.0f*w3 - 4.0f*w4 + w5;
    return fmaf(c0, B0, c1 * B1);
}

// oc [256 n][256 k] fp32 -> wb2: fragment-major bf16.
// group g = ((kk*16 + jn)*4 + quad)*16 + mrow  holds  W[n=jn*16+mrow][k=kk*32+quad*8 .. +8].
// Then wave load for (kk,j): lane(quad,mrow) reads wb2[kk*1024 + j*64 + quad*16 + mrow]
// = base + lane -> perfectly coalesced 1 KB per fragment.
__global__ void conv_w(const float* __restrict__ oc, const float* __restrict__ ic,
                       short8* __restrict__ wb2, float2* __restrict__ ct) {
    const int g = blockIdx.x * 256 + threadIdx.x;   // 0..8191
    const int mrow = g & 15, quad = (g >> 4) & 3, jn = (g >> 6) & 15, kk = g >> 10;
    const int n = jn * 16 + mrow, kb = kk * 32 + quad * 8;
    const float* src = oc + n * 256 + kb;
    const float4 u0 = *(const float4*)(src);
    const float4 u1 = *(const float4*)(src + 4);
    short8 v;
    v[0] = (short)f2bf(u0.x); v[1] = (short)f2bf(u0.y);
    v[2] = (short)f2bf(u0.z); v[3] = (short)f2bf(u0.w);
    v[4] = (short)f2bf(u1.x); v[5] = (short)f2bf(u1.y);
    v[6] = (short)f2bf(u1.z); v[7] = (short)f2bf(u1.w);
    wb2[g] = v;
    if (g < 256)
        ct[g] = make_float2(ic[g * 5 + 0] * (1.0f / 6.0f), ic[g * 5 + 1] * (1.0f / 6.0f));
}

// Block: 256 threads (4 waves), BM=64 (16 rows per wave), BN=256, grid 1024. NO LDS.
__global__ __launch_bounds__(256) __attribute__((amdgpu_waves_per_eu(2, 2)))
void kan_fused(const float* __restrict__ x, const float4* __restrict__ ctf4,
               const short8* __restrict__ wb2, float* __restrict__ out)
{
    const int t    = threadIdx.x;
    const int lane = t & 63;
    const int mw   = t >> 6;          // wave's m-slice
    const int mrow = lane & 15;
    const int quad = lane >> 4;
    const int m0   = blockIdx.x * 64;

    // this lane's x: row m0+mw*16+mrow, cols kk*32 + quad*8 .. +8 (its exact A-frag k's)
    const float* xrow = x + (size_t)(m0 + mw * 16 + mrow) * 256 + quad * 8;
    const short8* bbase = wb2 + quad * 16 + mrow;   // + kk*1024 + j*64

    f32x4 acc[16];
    #pragma unroll
    for (int j = 0; j < 16; ++j) acc[j] = (f32x4){0.f, 0.f, 0.f, 0.f};

    // prefetch x chunk 0
    float4 xa = *(const float4*)(xrow);
    float4 xb = *(const float4*)(xrow + 4);

    #pragma unroll 1
    for (int kk = 0; kk < 8; ++kk) {
        // B fragments for this chunk: 16 coalesced dwordx4 (L1 broadcast across waves)
        const short8* bp = bbase + kk * 1024;
        short8 b[16];
        #pragma unroll
        for (int j = 0; j < 16; ++j) b[j] = bp[j * 64];

        // prefetch next chunk's x (in flight during spline)
        float4 nxa, nxb;
        if (kk < 7) {
            const float* p = xrow + (kk + 1) * 32;
            nxa = *(const float4*)(p);
            nxb = *(const float4*)(p + 4);
        }

        // coeffs for k = kk*32 + quad*8 .. +8 (2 KB table, L1-hot, quad-uniform)
        const float4 cf0 = ctf4[kk * 16 + quad * 4 + 0];
        const float4 cf1 = ctf4[kk * 16 + quad * 4 + 1];
        const float4 cf2 = ctf4[kk * 16 + quad * 4 + 2];
        const float4 cf3 = ctf4[kk * 16 + quad * 4 + 3];

        // spline -> this lane's A-fragment (A[m=mrow][k=quad*8+e]) directly in regs
        short8 a;
        a[0] = (short)f2bf(inner_eval(xa.x, cf0.x, cf0.y));
        a[1] = (short)f2bf(inner_eval(xa.y, cf0.z, cf0.w));
        a[2] = (short)f2bf(inner_eval(xa.z, cf1.x, cf1.y));
        a[3] = (short)f2bf(inner_eval(xa.w, cf1.z, cf1.w));
        a[4] = (short)f2bf(inner_eval(xb.x, cf2.x, cf2.y));
        a[5] = (short)f2bf(inner_eval(xb.y, cf2.z, cf2.w));
        a[6] = (short)f2bf(inner_eval(xb.z, cf3.x, cf3.y));
        a[7] = (short)f2bf(inner_eval(xb.w, cf3.z, cf3.w));

        #pragma unroll
        for (int j = 0; j < 16; ++j)
            acc[j] = __builtin_amdgcn_mfma_f32_16x16x32_bf16(a, b[j], acc[j], 0, 0, 0);

        if (kk < 7) { xa = nxa; xb = nxb; }
    }

    // epilogue: direct fp32 stores (C/D layout: col=lane&15 -> n, row=quad*4+reg -> m)
    const int mbase = m0 + mw * 16 + quad * 4;
    #pragma unroll
    for (int j = 0; j < 16; ++j) {
        #pragma unroll
        for (int r = 0; r < 4; ++r)
            out[(size_t)(mbase + r) * 256 + j * 16 + mrow] = acc[j][r];
    }
}

extern "C" void kernel_launch(void* const* d_in, const int* in_sizes, int n_in,
                              void* d_out, int out_size, void* d_ws, size_t ws_size,
                              hipStream_t stream) {
    const float* x  = (const float*)d_in[0];   // [16,4096,256] fp32
    const float* ic = (const float*)d_in[1];   // [256,5] fp32
    const float* oc = (const float*)d_in[2];   // [256,256] fp32

    short8* wb2 = (short8*)d_ws;                         // 128 KB frag-major bf16 W
    float2* ct  = (float2*)((char*)d_ws + 131072);       // 2 KB coeff/6 table

    conv_w<<<32, 256, 0, stream>>>(oc, ic, wb2, ct);
    kan_fused<<<1024, 256, 0, stream>>>(x, (const float4*)ct, wb2, (float*)d_out);
}

// Round 6
// 154.268 us; speedup vs baseline: 1.8286x; 1.0352x over previous
//
#include <hip/hip_runtime.h>
#include <stdint.h>

// KAN layer, MI355X (gfx950). R6 = R5 + occupancy 2->3 waves/EU.
// out[M=65536,N=256] (fp32) = A[M,K=256] @ W^T
//   A[m,k] = c0[k]*B0(tanh x[m,k]) + c1[k]*B1(tanh x[m,k])  (1/6 folded into c), bf16 in regs
// Wave mw owns rows [m0+16*mw, +16) x ALL n: each lane's spline outputs ARE its MFMA
// A-fragment -> no A sharing, no LDS, no barriers. B-frags read per chunk from a
// fragment-major bf16 W (pre-permuted by conv_w; one coalesced dwordx4 per lane per frag).
// History: R3/R4 allocator spilled at high-occupancy targets (WRITE 66->261/291 MB).
// R5 waves_per_eu(2,2): no spill (WRITE 65.5 MB, VGPR 88+64 AGPR = 152) but 15% occupancy,
// all pipes <22% -> latency-bound. R6: waves_per_eu(3,3) = 170-reg budget, 152 live fits.

typedef __attribute__((ext_vector_type(8))) short short8;   // 8 bf16 (MFMA A/B frag)
typedef __attribute__((ext_vector_type(4))) float f32x4;    // MFMA C/D frag

__device__ __forceinline__ uint16_t f2bf(float f) {
    union { float f; uint32_t u; } v; v.f = f;
    uint32_t r = v.u + 0x7FFFu + ((v.u >> 16) & 1u);  // RNE
    return (uint16_t)(r >> 16);
}

__device__ __forceinline__ float cube_relu(float v) {
    float m = fmaxf(v, 0.0f);
    return m * m * m;
}

// c0,c1 pre-scaled by 1/6 (conv_w). Uniform knots h=2/7 on [-1,1]; u=(tanh+1)*3.5 in [0,7].
__device__ __forceinline__ float inner_eval(float xx, float c0, float c1) {
    float e  = __expf(2.0f * xx);                       // tanh = 1 - 2/(e+1)
    float r  = __builtin_amdgcn_rcpf(e + 1.0f);
    float u  = fmaf(-7.0f, r, 7.0f);
    float w0 = cube_relu(u);
    float w1 = cube_relu(u - 1.0f);
    float w2 = cube_relu(u - 2.0f);
    float w3 = cube_relu(u - 3.0f);
    float w4 = cube_relu(u - 4.0f);
    float w5 = cube_relu(u - 5.0f);
    float B0 = w0 - 4.0f*w1 + 6.0f*w2 - 4.0f*w3 + w4;
    float B1 = w1 - 4.0f*w2 + 6.0f*w3 - 4.0f*w4 + w5;
    return fmaf(c0, B0, c1 * B1);
}

// oc [256 n][256 k] fp32 -> wb2: fragment-major bf16.
// group g = ((kk*16 + jn)*4 + quad)*16 + mrow  holds  W[n=jn*16+mrow][k=kk*32+quad*8 .. +8].
// Wave load for (kk,j): lane(quad,mrow) reads wb2[kk*1024 + j*64 + quad*16 + mrow]
// = base + lane -> perfectly coalesced 1 KB per fragment.
__global__ void conv_w(const float* __restrict__ oc, const float* __restrict__ ic,
                       short8* __restrict__ wb2, float2* __restrict__ ct) {
    const int g = blockIdx.x * 256 + threadIdx.x;   // 0..8191
    const int mrow = g & 15, quad = (g >> 4) & 3, jn = (g >> 6) & 15, kk = g >> 10;
    const int n = jn * 16 + mrow, kb = kk * 32 + quad * 8;
    const float* src = oc + n * 256 + kb;
    const float4 u0 = *(const float4*)(src);
    const float4 u1 = *(const float4*)(src + 4);
    short8 v;
    v[0] = (short)f2bf(u0.x); v[1] = (short)f2bf(u0.y);
    v[2] = (short)f2bf(u0.z); v[3] = (short)f2bf(u0.w);
    v[4] = (short)f2bf(u1.x); v[5] = (short)f2bf(u1.y);
    v[6] = (short)f2bf(u1.z); v[7] = (short)f2bf(u1.w);
    wb2[g] = v;
    if (g < 256)
        ct[g] = make_float2(ic[g * 5 + 0] * (1.0f / 6.0f), ic[g * 5 + 1] * (1.0f / 6.0f));
}

// Block: 256 threads (4 waves), BM=64 (16 rows per wave), BN=256, grid 1024. NO LDS.
__global__ __launch_bounds__(256) __attribute__((amdgpu_waves_per_eu(3, 3)))
void kan_fused(const float* __restrict__ x, const float4* __restrict__ ctf4,
               const short8* __restrict__ wb2, float* __restrict__ out)
{
    const int t    = threadIdx.x;
    const int lane = t & 63;
    const int mw   = t >> 6;          // wave's m-slice
    const int mrow = lane & 15;
    const int quad = lane >> 4;
    const int m0   = blockIdx.x * 64;

    // this lane's x: row m0+mw*16+mrow, cols kk*32 + quad*8 .. +8 (its exact A-frag k's)
    const float* xrow = x + (size_t)(m0 + mw * 16 + mrow) * 256 + quad * 8;
    const short8* bbase = wb2 + quad * 16 + mrow;   // + kk*1024 + j*64

    f32x4 acc[16];
    #pragma unroll
    for (int j = 0; j < 16; ++j) acc[j] = (f32x4){0.f, 0.f, 0.f, 0.f};

    // prefetch x chunk 0
    float4 xa = *(const float4*)(xrow);
    float4 xb = *(const float4*)(xrow + 4);

    #pragma unroll 1
    for (int kk = 0; kk < 8; ++kk) {
        // B fragments for this chunk: 16 coalesced dwordx4 (L1/L2-hot, identical across waves)
        const short8* bp = bbase + kk * 1024;
        short8 b[16];
        #pragma unroll
        for (int j = 0; j < 16; ++j) b[j] = bp[j * 64];

        // prefetch next chunk's x AFTER b-loads (so MFMA's wait on b[15] is vmcnt(2), not 0)
        float4 nxa, nxb;
        if (kk < 7) {
            const float* p = xrow + (kk + 1) * 32;
            nxa = *(const float4*)(p);
            nxb = *(const float4*)(p + 4);
        }

        // coeffs for k = kk*32 + quad*8 .. +8 (2 KB table, L1-hot, quad-uniform)
        const float4 cf0 = ctf4[kk * 16 + quad * 4 + 0];
        const float4 cf1 = ctf4[kk * 16 + quad * 4 + 1];
        const float4 cf2 = ctf4[kk * 16 + quad * 4 + 2];
        const float4 cf3 = ctf4[kk * 16 + quad * 4 + 3];

        // spline -> this lane's A-fragment (A[m=mrow][k=quad*8+e]) directly in regs
        short8 a;
        a[0] = (short)f2bf(inner_eval(xa.x, cf0.x, cf0.y));
        a[1] = (short)f2bf(inner_eval(xa.y, cf0.z, cf0.w));
        a[2] = (short)f2bf(inner_eval(xa.z, cf1.x, cf1.y));
        a[3] = (short)f2bf(inner_eval(xa.w, cf1.z, cf1.w));
        a[4] = (short)f2bf(inner_eval(xb.x, cf2.x, cf2.y));
        a[5] = (short)f2bf(inner_eval(xb.y, cf2.z, cf2.w));
        a[6] = (short)f2bf(inner_eval(xb.z, cf3.x, cf3.y));
        a[7] = (short)f2bf(inner_eval(xb.w, cf3.z, cf3.w));

        #pragma unroll
        for (int j = 0; j < 16; ++j)
            acc[j] = __builtin_amdgcn_mfma_f32_16x16x32_bf16(a, b[j], acc[j], 0, 0, 0);

        if (kk < 7) { xa = nxa; xb = nxb; }
    }

    // epilogue: direct fp32 stores (C/D layout: col=lane&15 -> n, row=quad*4+reg -> m)
    const int mbase = m0 + mw * 16 + quad * 4;
    #pragma unroll
    for (int j = 0; j < 16; ++j) {
        #pragma unroll
        for (int r = 0; r < 4; ++r)
            out[(size_t)(mbase + r) * 256 + j * 16 + mrow] = acc[j][r];
    }
}

extern "C" void kernel_launch(void* const* d_in, const int* in_sizes, int n_in,
                              void* d_out, int out_size, void* d_ws, size_t ws_size,
                              hipStream_t stream) {
    const float* x  = (const float*)d_in[0];   // [16,4096,256] fp32
    const float* ic = (const float*)d_in[1];   // [256,5] fp32
    const float* oc = (const float*)d_in[2];   // [256,256] fp32

    short8* wb2 = (short8*)d_ws;                         // 128 KB frag-major bf16 W
    float2* ct  = (float2*)((char*)d_ws + 131072);       // 2 KB coeff/6 table

    conv_w<<<32, 256, 0, stream>>>(oc, ic, wb2, ct);
    kan_fused<<<1024, 256, 0, stream>>>(x, (const float4*)ct, wb2, (float*)d_out);
}